// Round 4
// baseline (1335.239 us; speedup 1.0000x reference)
//
#include <hip/hip_runtime.h>
#include <stdint.h>

#define NN 100000
#define EE 1600000
#define DD 256
#define NSTRIP 6250          // NN / 16
#define TOTW 2048            // 256 pair-blocks * 8 waves

typedef __bf16 bf16;
typedef __attribute__((ext_vector_type(8))) __bf16 bf16x8;
typedef __attribute__((ext_vector_type(4))) float f32x4;
typedef __attribute__((ext_vector_type(4))) unsigned int u32x4;
typedef __attribute__((ext_vector_type(8))) unsigned short u16x8;

typedef __attribute__((address_space(1))) const unsigned int g_u32c;
typedef __attribute__((address_space(3))) unsigned int lds_u32;

__device__ __forceinline__ float bflo(unsigned int u) {
    union { unsigned int u; float f; } x; x.u = u << 16; return x.f;
}
__device__ __forceinline__ float bfhi(unsigned int u) {
    union { unsigned int u; float f; } x; x.u = u & 0xFFFF0000u; return x.f;
}
__device__ __forceinline__ unsigned short f2bf(float f) {
    return __builtin_bit_cast(unsigned short, (__bf16)f);
}
__device__ __forceinline__ float mask_fac(const void* mask, size_t idx, int byteMode) {
    if (byteMode) return ((const unsigned char*)mask)[idx] ? 2.0f : 0.0f;
    return ((const unsigned int*)mask)[idx] ? 2.0f : 0.0f;
}

// ---------------------------------------------------------------------------
// CSR build
// ---------------------------------------------------------------------------
__global__ void count_deg_k(const int* __restrict__ dst, int* __restrict__ cnt) {
    int e = blockIdx.x * 256 + threadIdx.x;
    if (e < EE) atomicAdd(&cnt[__builtin_nontemporal_load(dst + e)], 1);
}
__global__ __launch_bounds__(256) void scan_blk_k(const int* __restrict__ cnt,
                                                  int* __restrict__ part,
                                                  int* __restrict__ bsum,
                                                  float* __restrict__ dinv) {
    __shared__ int buf[256];
    int i = blockIdx.x * 256 + threadIdx.x;
    int v = 0;
    if (i < NN) { v = cnt[i] + 1; dinv[i] = rsqrtf((float)v); }   // +1 self-loop
    buf[threadIdx.x] = v;
    __syncthreads();
    for (int off = 1; off < 256; off <<= 1) {
        int t = (threadIdx.x >= off) ? buf[threadIdx.x - off] : 0;
        __syncthreads();
        buf[threadIdx.x] += t;
        __syncthreads();
    }
    if (i < NN) part[i] = buf[threadIdx.x];
    if (threadIdx.x == 255) bsum[blockIdx.x] = buf[255];
}
__global__ __launch_bounds__(512) void scan_top_k(const int* __restrict__ bsum,
                                                  int* __restrict__ bpre, int nb) {
    __shared__ int buf[512];
    int v = (threadIdx.x < (unsigned)nb) ? bsum[threadIdx.x] : 0;
    buf[threadIdx.x] = v;
    __syncthreads();
    for (int off = 1; off < 512; off <<= 1) {
        int t = (threadIdx.x >= off) ? buf[threadIdx.x - off] : 0;
        __syncthreads();
        buf[threadIdx.x] += t;
        __syncthreads();
    }
    if (threadIdx.x < (unsigned)nb) bpre[threadIdx.x] = buf[threadIdx.x] - v;
}
__global__ void scan_fin_k(const int* __restrict__ part, const int* __restrict__ bpre,
                           const int* __restrict__ cnt, const float* __restrict__ dinv,
                           int* __restrict__ offs, int* __restrict__ cur,
                           int* __restrict__ cs, float* __restrict__ cw) {
    int i = blockIdx.x * 256 + threadIdx.x;
    if (i >= NN) return;
    int o1 = part[i] + bpre[blockIdx.x];
    offs[i + 1] = o1;
    if (i == 0) offs[0] = 0;
    int o = o1 - (cnt[i] + 1);
    cs[o] = i;
    float di = dinv[i];
    cw[o] = di * di;
    cur[i] = o + 1;
}
__global__ void fill_csr_k(const int* __restrict__ src, const int* __restrict__ dst,
                           const float* __restrict__ dinv, int* __restrict__ cur,
                           int* __restrict__ cs, float* __restrict__ cw) {
    int e = blockIdx.x * 256 + threadIdx.x;
    if (e >= EE) return;
    int s = __builtin_nontemporal_load(src + e);
    int d = __builtin_nontemporal_load(dst + e);
    int pos = atomicAdd(&cur[d], 1);
    cs[pos] = s;
    cw[pos] = dinv[s] * dinv[d];
}

// ---------------------------------------------------------------------------
// prep: Wt[n][k] = (bf16)W[k][n] for 3 weights (blocks 0..191) + mask probe (192)
// ---------------------------------------------------------------------------
__global__ __launch_bounds__(256) void prep_k(
    const float* __restrict__ W0, const float* __restrict__ W1, const float* __restrict__ W2,
    bf16* __restrict__ T0, bf16* __restrict__ T1, bf16* __restrict__ T2,
    const unsigned int* __restrict__ m, int* __restrict__ flag) {
    int b = blockIdx.x;
    if (b == 192) {
        if (threadIdx.x < 64) {
            unsigned int v = m[threadIdx.x];
            int bad = (v > 1u && v != 0x3F800000u) ? 1 : 0;
            unsigned long long bl = __ballot(bad);
            if (threadIdx.x == 0) *flag = (bl != 0ull) ? 1 : 0;
        }
        return;
    }
    const float* W = b < 64 ? W0 : (b < 128 ? W1 : W2);
    bf16*       T  = b < 64 ? T0 : (b < 128 ? T1 : T2);
    int bb = b & 63;
    __shared__ float tile[32][33];
    int bx = bb & 7, by = bb >> 3;
    int tx = threadIdx.x & 31, ty = threadIdx.x >> 5;
    #pragma unroll
    for (int r = 0; r < 32; r += 8)
        tile[ty + r][tx] = W[(size_t)(by * 32 + ty + r) * DD + bx * 32 + tx];
    __syncthreads();
    #pragma unroll
    for (int r = 0; r < 32; r += 8)
        T[(size_t)(bx * 32 + ty + r) * DD + by * 32 + tx] = (bf16)tile[tx][ty + r];
}

// ---------------------------------------------------------------------------
// Persistent-B streaming GEMM.
// Grid: 512 blocks x 512 thr. Block -> (pair p, n-half h); pair members share
// XCD (same bid%8) so the A strips they both read hit the same L2.
// B panel (128 n x 256 k bf16 = 64 KB) staged once, XOR-swizzled
// (chunk' = chunk ^ (n&31)); then ZERO barriers: each wave streams 16-row A
// strips (A frags per-lane direct from global, double-buffered across strips).
// EPI 1: +bias, relu, dropout(mask) -> bf16.  EPI 2: +bias, * z -> fp32.
// F32A : A is fp32 (omega), converted in-register.
// ---------------------------------------------------------------------------
template <int EPI, int F32A>
__global__ __launch_bounds__(512, 4) void gemm_k(
    const void* __restrict__ Ap, const bf16* __restrict__ Wt,
    const float* __restrict__ bias, const void* __restrict__ mask,
    const int* __restrict__ flagp, const float* __restrict__ z,
    void* __restrict__ outp) {
    __shared__ __align__(16) bf16 Bs[128 * 256];   // 64 KB

    int bid = blockIdx.x;                          // 0..511
    int p   = ((bid >> 4) << 3) | (bid & 7);       // pair 0..255
    int h   = (bid >> 3) & 1;                      // n-half
    int n0  = h * 128;
    int tid = threadIdx.x;
    int wid = tid >> 6, lane = tid & 63;
    int lr = lane & 15, lk = lane >> 4;

    // stage B: linear LDS dest + inverse-swizzled global source (rule 21)
    #pragma unroll
    for (int i = 0; i < 8; i++) {
        int c = i * 512 + tid;                     // 16B chunk 0..4095
        int n = c >> 5, pos = c & 31;
        int g = pos ^ (n & 31);
        __builtin_amdgcn_global_load_lds(
            (g_u32c*)(Wt + (size_t)(n0 + n) * DD + g * 8),
            (lds_u32*)(Bs + (size_t)c * 8), 16, 0, 0);
    }
    __syncthreads();                               // the only barrier

    float breg[8];
    #pragma unroll
    for (int ni = 0; ni < 8; ni++) breg[ni] = bias[n0 + ni * 16 + lr];
    int bm = (EPI == 1) ? *flagp : 0;

    int gw = p * 8 + wid;                          // 0..2047

    bf16x8 cur[8], nxt[8];
    auto loadA = [&](int s, bf16x8* fr) {
        if (F32A) {
            const float* A = (const float*)Ap + (size_t)(s * 16 + lr) * DD + lk * 8;
            #pragma unroll
            for (int kk = 0; kk < 8; kk++) {
                float4 v0 = *(const float4*)(A + kk * 32);
                float4 v1 = *(const float4*)(A + kk * 32 + 4);
                bf16x8 f;
                f[0] = (bf16)v0.x; f[1] = (bf16)v0.y; f[2] = (bf16)v0.z; f[3] = (bf16)v0.w;
                f[4] = (bf16)v1.x; f[5] = (bf16)v1.y; f[6] = (bf16)v1.z; f[7] = (bf16)v1.w;
                fr[kk] = f;
            }
        } else {
            const bf16* A = (const bf16*)Ap + (size_t)(s * 16 + lr) * DD + lk * 8;
            #pragma unroll
            for (int kk = 0; kk < 8; kk++)
                fr[kk] = *(const bf16x8*)(A + kk * 32);
        }
    };

    int s = gw;
    if (s < NSTRIP) loadA(s, cur);
    while (s < NSTRIP) {
        int sn = s + TOTW;
        if (sn < NSTRIP) loadA(sn, nxt);           // prefetch next strip

        f32x4 acc[8] = {};
        #pragma unroll
        for (int kk = 0; kk < 8; kk++) {
            #pragma unroll
            for (int ni = 0; ni < 8; ni++) {
                int n = ni * 16 + lr;
                int chunk = (kk * 4 + lk) ^ (n & 31);
                bf16x8 bf = *(const bf16x8*)(Bs + (size_t)n * DD + chunk * 8);
                acc[ni] = __builtin_amdgcn_mfma_f32_16x16x32_bf16(cur[kk], bf, acc[ni], 0, 0, 0);
            }
        }

        int row0 = s * 16 + lk * 4;                // C/D: row=(lane>>4)*4+reg
        #pragma unroll
        for (int ni = 0; ni < 8; ni++) {
            int gc = n0 + ni * 16 + lr;            // col = lane&15
            #pragma unroll
            for (int r = 0; r < 4; r++) {
                size_t idx = (size_t)(row0 + r) * DD + gc;
                float v = acc[ni][r] + breg[ni];
                if (EPI == 1) {
                    v = fmaxf(v, 0.f) * mask_fac(mask, idx, bm);
                    ((bf16*)outp)[idx] = (bf16)v;
                } else {
                    v *= __builtin_nontemporal_load(z + idx);
                    __builtin_nontemporal_store(v, (float*)outp + idx);
                }
            }
        }
        #pragma unroll
        for (int kk = 0; kk < 8; kk++) cur[kk] = nxt[kk];
        s = sn;
    }
}

// ---------------------------------------------------------------------------
// Pure CSR gather: out[n,:] = sum_e w[e] * t[src[e],:]   (bf16 rows, fp32 acc)
// One wave per node; 32 lanes x 16B cover one row -> 2 rows in flight/wave.
// ---------------------------------------------------------------------------
__global__ __launch_bounds__(256) void agg_k(
    const bf16* __restrict__ t, const int* __restrict__ offs,
    const int* __restrict__ cs, const float* __restrict__ cw,
    bf16* __restrict__ out) {
    int node = blockIdx.x * 4 + (threadIdx.x >> 6);
    if (node >= NN) return;
    int lane = threadIdx.x & 63;
    int half = lane >> 5;
    int lc = lane & 31;
    int beg = offs[node], end = offs[node + 1];

    float acc[8] = {};
    const unsigned short* tb = (const unsigned short*)t;
    for (int base = beg; base < end; base += 64) {
        int nume = min(64, end - base);
        int sl = 0; float wl = 0.f;
        if (lane < nume) {
            sl = __builtin_nontemporal_load(cs + base + lane);
            wl = __builtin_nontemporal_load(cw + base + lane);
        }
        int nit = (nume + 1) >> 1;
        for (int j = 0; j < nit; j++) {
            int idx = 2 * j + half;
            int s   = __shfl(sl, idx);
            float w = __shfl(wl, idx);
            u32x4 u = *(const u32x4*)(tb + (size_t)s * DD + lc * 8);
            acc[0] = fmaf(w, bflo(u.x), acc[0]);
            acc[1] = fmaf(w, bfhi(u.x), acc[1]);
            acc[2] = fmaf(w, bflo(u.y), acc[2]);
            acc[3] = fmaf(w, bfhi(u.y), acc[3]);
            acc[4] = fmaf(w, bflo(u.z), acc[4]);
            acc[5] = fmaf(w, bfhi(u.z), acc[5]);
            acc[6] = fmaf(w, bflo(u.w), acc[6]);
            acc[7] = fmaf(w, bfhi(u.w), acc[7]);
        }
    }
    #pragma unroll
    for (int i = 0; i < 8; i++) acc[i] += __shfl_xor(acc[i], 32);
    if (half == 0) {
        u16x8 o = { f2bf(acc[0]), f2bf(acc[1]), f2bf(acc[2]), f2bf(acc[3]),
                    f2bf(acc[4]), f2bf(acc[5]), f2bf(acc[6]), f2bf(acc[7]) };
        __builtin_nontemporal_store(o, (u16x8*)((unsigned short*)out + (size_t)node * DD + lc * 8));
    }
}

// ---------------------------------------------------------------------------
extern "C" void kernel_launch(void* const* d_in, const int* in_sizes, int n_in,
                              void* d_out, int out_size, void* d_ws, size_t ws_size,
                              hipStream_t stream) {
    const float* z     = (const float*)d_in[0];
    const float* omega = (const float*)d_in[1];
    const int*   eidx  = (const int*)d_in[2];
    const float* W_lin = (const float*)d_in[3];
    const float* b_lin = (const float*)d_in[4];
    const float* W_g1  = (const float*)d_in[5];
    const float* b_g1  = (const float*)d_in[6];
    const float* W_g2  = (const float*)d_in[7];
    const float* b_g2  = (const float*)d_in[8];
    const void*  mask1 = d_in[9];
    const void*  mask2 = d_in[10];

    const int* e_src = eidx;
    const int* e_dst = eidx + EE;

    char* p = (char*)d_ws;
    size_t off = 0;
    auto alloc = [&](size_t bytes) -> char* {
        char* r = p + off;
        off = (off + bytes + 255) & ~(size_t)255;
        return r;
    };
    const int NB256 = (NN + 255) / 256;          // 391
    int*   flag = (int*)  alloc(4);
    int*   cnt  = (int*)  alloc((size_t)NN * 4);
    int*   offs = (int*)  alloc(((size_t)NN + 1) * 4);
    int*   cur  = (int*)  alloc((size_t)NN * 4);
    int*   part = (int*)  alloc((size_t)NN * 4);
    int*   bsum = (int*)  alloc(512 * 4);
    int*   bpre = (int*)  alloc(512 * 4);
    float* dinv = (float*)alloc((size_t)NN * 4);
    int*   cs   = (int*)  alloc((size_t)(EE + NN) * 4);
    float* cw   = (float*)alloc((size_t)(EE + NN) * 4);
    bf16*  WtL  = (bf16*) alloc((size_t)DD * DD * 2);
    bf16*  Wt1  = (bf16*) alloc((size_t)DD * DD * 2);
    bf16*  Wt2  = (bf16*) alloc((size_t)DD * DD * 2);
    const size_t NBH = (size_t)NN * DD * 2;      // 51.2 MB bf16 slab
    bf16*  S1   = (bf16*) alloc(NBH);
    bf16*  S2   = (bf16*) alloc(NBH);

    // --- CSR build ---
    hipMemsetAsync(cnt, 0, (size_t)NN * 4, stream);
    count_deg_k<<<EE / 256, 256, 0, stream>>>(e_dst, cnt);
    scan_blk_k <<<NB256, 256, 0, stream>>>(cnt, part, bsum, dinv);
    scan_top_k <<<1, 512, 0, stream>>>(bsum, bpre, NB256);
    scan_fin_k <<<NB256, 256, 0, stream>>>(part, bpre, cnt, dinv, offs, cur, cs, cw);
    fill_csr_k <<<EE / 256, 256, 0, stream>>>(e_src, e_dst, dinv, cur, cs, cw);

    // --- weight transpose-cvt + mask probe ---
    prep_k<<<193, 256, 0, stream>>>(W_lin, W_g1, W_g2, WtL, Wt1, Wt2,
                                    (const unsigned int*)mask1, flag);

    // --- pipeline: GCNConv reordered as (A_hat . X) . W ---
    // h0 = dropout(relu(omega @ W_lin + b_lin))        (f32 A, fused cvt) -> S1
    gemm_k<1, 1><<<512, 512, 0, stream>>>(omega, WtL, b_lin, mask1, flag, nullptr, S1);
    // g1 = A_hat . h0                                   S1 -> S2
    agg_k<<<NN / 4, 256, 0, stream>>>(S1, offs, cs, cw, S2);
    // h1 = dropout(relu(g1 @ W_g1 + b_g1))              S2 -> S1
    gemm_k<1, 0><<<512, 512, 0, stream>>>(S2, Wt1, b_g1, mask2, flag, nullptr, S1);
    // g2 = A_hat . h1                                   S1 -> S2
    agg_k<<<NN / 4, 256, 0, stream>>>(S1, offs, cs, cw, S2);
    // out = z * (g2 @ W_g2 + b_g2)                      S2 -> d_out (fp32, nt)
    gemm_k<2, 0><<<512, 512, 0, stream>>>(S2, Wt2, b_g2, nullptr, flag, z, d_out);
}

// Round 5
// 1233.587 us; speedup vs baseline: 1.0824x; 1.0824x over previous
//
#include <hip/hip_runtime.h>
#include <stdint.h>

#define NN 100000
#define EE 1600000
#define DD 256
#define NSTRIP 6250          // NN / 16
#define TOTW 2048            // 256 pair-blocks * 8 waves

typedef __bf16 bf16;
typedef __attribute__((ext_vector_type(8))) __bf16 bf16x8;
typedef __attribute__((ext_vector_type(4))) float f32x4;
typedef __attribute__((ext_vector_type(4))) unsigned int u32x4;
typedef __attribute__((ext_vector_type(8))) unsigned short u16x8;

typedef __attribute__((address_space(1))) const unsigned int g_u32c;
typedef __attribute__((address_space(3))) unsigned int lds_u32;

__device__ __forceinline__ float bflo(unsigned int u) {
    union { unsigned int u; float f; } x; x.u = u << 16; return x.f;
}
__device__ __forceinline__ float bfhi(unsigned int u) {
    union { unsigned int u; float f; } x; x.u = u & 0xFFFF0000u; return x.f;
}
__device__ __forceinline__ unsigned short f2bf(float f) {
    return __builtin_bit_cast(unsigned short, (__bf16)f);
}
__device__ __forceinline__ float mask_fac(const void* mask, size_t idx, int byteMode) {
    if (byteMode) return ((const unsigned char*)mask)[idx] ? 2.0f : 0.0f;
    return ((const unsigned int*)mask)[idx] ? 2.0f : 0.0f;
}

// ---------------------------------------------------------------------------
// CSR build
// ---------------------------------------------------------------------------
__global__ void count_deg_k(const int* __restrict__ dst, int* __restrict__ cnt) {
    int e = blockIdx.x * 256 + threadIdx.x;
    if (e < EE) atomicAdd(&cnt[__builtin_nontemporal_load(dst + e)], 1);
}
__global__ __launch_bounds__(256) void scan_blk_k(const int* __restrict__ cnt,
                                                  int* __restrict__ part,
                                                  int* __restrict__ bsum,
                                                  float* __restrict__ dinv) {
    __shared__ int buf[256];
    int i = blockIdx.x * 256 + threadIdx.x;
    int v = 0;
    if (i < NN) { v = cnt[i] + 1; dinv[i] = rsqrtf((float)v); }   // +1 self-loop
    buf[threadIdx.x] = v;
    __syncthreads();
    for (int off = 1; off < 256; off <<= 1) {
        int t = (threadIdx.x >= off) ? buf[threadIdx.x - off] : 0;
        __syncthreads();
        buf[threadIdx.x] += t;
        __syncthreads();
    }
    if (i < NN) part[i] = buf[threadIdx.x];
    if (threadIdx.x == 255) bsum[blockIdx.x] = buf[255];
}
__global__ __launch_bounds__(512) void scan_top_k(const int* __restrict__ bsum,
                                                  int* __restrict__ bpre, int nb) {
    __shared__ int buf[512];
    int v = (threadIdx.x < (unsigned)nb) ? bsum[threadIdx.x] : 0;
    buf[threadIdx.x] = v;
    __syncthreads();
    for (int off = 1; off < 512; off <<= 1) {
        int t = (threadIdx.x >= off) ? buf[threadIdx.x - off] : 0;
        __syncthreads();
        buf[threadIdx.x] += t;
        __syncthreads();
    }
    if (threadIdx.x < (unsigned)nb) bpre[threadIdx.x] = buf[threadIdx.x] - v;
}
__global__ void scan_fin_k(const int* __restrict__ part, const int* __restrict__ bpre,
                           const int* __restrict__ cnt, const float* __restrict__ dinv,
                           int* __restrict__ offs, int* __restrict__ cur,
                           int* __restrict__ cs, float* __restrict__ cw) {
    int i = blockIdx.x * 256 + threadIdx.x;
    if (i >= NN) return;
    int o1 = part[i] + bpre[blockIdx.x];
    offs[i + 1] = o1;
    if (i == 0) offs[0] = 0;
    int o = o1 - (cnt[i] + 1);
    cs[o] = i;
    float di = dinv[i];
    cw[o] = di * di;
    cur[i] = o + 1;
}
__global__ void fill_csr_k(const int* __restrict__ src, const int* __restrict__ dst,
                           const float* __restrict__ dinv, int* __restrict__ cur,
                           int* __restrict__ cs, float* __restrict__ cw) {
    int e = blockIdx.x * 256 + threadIdx.x;
    if (e >= EE) return;
    int s = __builtin_nontemporal_load(src + e);
    int d = __builtin_nontemporal_load(dst + e);
    int pos = atomicAdd(&cur[d], 1);
    cs[pos] = s;
    cw[pos] = dinv[s] * dinv[d];
}

// ---------------------------------------------------------------------------
// prep: Wt[n][k] = (bf16)W[k][n] for 3 weights (blocks 0..191) + mask probe (192)
// ---------------------------------------------------------------------------
__global__ __launch_bounds__(256) void prep_k(
    const float* __restrict__ W0, const float* __restrict__ W1, const float* __restrict__ W2,
    bf16* __restrict__ T0, bf16* __restrict__ T1, bf16* __restrict__ T2,
    const unsigned int* __restrict__ m, int* __restrict__ flag) {
    int b = blockIdx.x;
    if (b == 192) {
        if (threadIdx.x < 64) {
            unsigned int v = m[threadIdx.x];
            int bad = (v > 1u && v != 0x3F800000u) ? 1 : 0;
            unsigned long long bl = __ballot(bad);
            if (threadIdx.x == 0) *flag = (bl != 0ull) ? 1 : 0;
        }
        return;
    }
    const float* W = b < 64 ? W0 : (b < 128 ? W1 : W2);
    bf16*       T  = b < 64 ? T0 : (b < 128 ? T1 : T2);
    int bb = b & 63;
    __shared__ float tile[32][33];
    int bx = bb & 7, by = bb >> 3;
    int tx = threadIdx.x & 31, ty = threadIdx.x >> 5;
    #pragma unroll
    for (int r = 0; r < 32; r += 8)
        tile[ty + r][tx] = W[(size_t)(by * 32 + ty + r) * DD + bx * 32 + tx];
    __syncthreads();
    #pragma unroll
    for (int r = 0; r < 32; r += 8)
        T[(size_t)(bx * 32 + ty + r) * DD + by * 32 + tx] = (bf16)tile[tx][ty + r];
}

// ---------------------------------------------------------------------------
// Persistent-B streaming GEMM (spill-free).
// Grid: 512 blocks x 512 thr (8 waves). Block -> (pair p, n-half h); the two
// pair members share bid%8 (same XCD) so their shared A strips hit one L2.
// B panel (128 n x 256 k bf16 = 64 KB) staged once, XOR-swizzled
// (chunk' = chunk ^ (n&31)); then ZERO barriers. Each wave streams 16-row A
// strips: A fragments per-lane direct global->reg (single-buffered; TLP from
// 16 waves/CU hides latency), accumulator reordered so only ONE f32x4 acc is
// live (per-ni dependent MFMA chain), epilogue fused per ni.
// EPI 1: +bias, relu, dropout(mask) -> bf16.  EPI 2: +bias, * z -> fp32.
// F32A : A is fp32 (omega), converted in-register.
// ---------------------------------------------------------------------------
template <int EPI, int F32A>
__global__ __launch_bounds__(512, 4) void gemm_k(
    const void* __restrict__ Ap, const bf16* __restrict__ Wt,
    const float* __restrict__ bias, const void* __restrict__ mask,
    const int* __restrict__ flagp, const float* __restrict__ z,
    void* __restrict__ outp) {
    __shared__ __align__(16) bf16 Bs[128 * 256];   // 64 KB

    int bid = blockIdx.x;                          // 0..511
    int p   = ((bid >> 4) << 3) | (bid & 7);       // pair 0..255
    int h   = (bid >> 3) & 1;                      // n-half
    int n0  = h * 128;
    int tid = threadIdx.x;
    int wid = tid >> 6, lane = tid & 63;
    int lr = lane & 15, lk = lane >> 4;

    // stage B: linear LDS dest + inverse-swizzled global source (rule 21)
    #pragma unroll
    for (int i = 0; i < 8; i++) {
        int c = i * 512 + tid;                     // 16B chunk 0..4095
        int n = c >> 5, pos = c & 31;
        int g = pos ^ (n & 31);
        __builtin_amdgcn_global_load_lds(
            (g_u32c*)(Wt + (size_t)(n0 + n) * DD + g * 8),
            (lds_u32*)(Bs + (size_t)c * 8), 16, 0, 0);
    }
    __syncthreads();                               // the only barrier

    float breg[8];
    #pragma unroll
    for (int ni = 0; ni < 8; ni++) breg[ni] = bias[n0 + ni * 16 + lr];
    int bm = (EPI == 1) ? *flagp : 0;

    for (int s = p * 8 + wid; s < NSTRIP; s += TOTW) {
        // ---- load A fragments for this strip (straight-line, SROA-safe) ----
        bf16x8 afr[8];
        if (F32A) {
            const float* A = (const float*)Ap + (size_t)(s * 16 + lr) * DD + lk * 8;
            #pragma unroll
            for (int kk = 0; kk < 8; kk++) {
                float4 v0 = *(const float4*)(A + kk * 32);
                float4 v1 = *(const float4*)(A + kk * 32 + 4);
                bf16x8 f;
                f[0] = (bf16)v0.x; f[1] = (bf16)v0.y; f[2] = (bf16)v0.z; f[3] = (bf16)v0.w;
                f[4] = (bf16)v1.x; f[5] = (bf16)v1.y; f[6] = (bf16)v1.z; f[7] = (bf16)v1.w;
                afr[kk] = f;
            }
        } else {
            const bf16* A = (const bf16*)Ap + (size_t)(s * 16 + lr) * DD + lk * 8;
            #pragma unroll
            for (int kk = 0; kk < 8; kk++)
                afr[kk] = *(const bf16x8*)(A + kk * 32);
        }

        int row0 = s * 16 + lk * 4;                // C/D: row=(lane>>4)*4+reg
        #pragma unroll
        for (int ni = 0; ni < 8; ni++) {
            int n = ni * 16 + lr;
            const bf16* Brow = Bs + (size_t)n * DD;
            f32x4 acc = {};
            #pragma unroll
            for (int kk = 0; kk < 8; kk++) {
                int chunk = (kk * 4 + lk) ^ (n & 31);
                acc = __builtin_amdgcn_mfma_f32_16x16x32_bf16(
                    afr[kk], *(const bf16x8*)(Brow + chunk * 8), acc, 0, 0, 0);
            }
            int gc = n0 + n;                       // col = lane&15 within frag
            float bb = breg[ni];
            #pragma unroll
            for (int r = 0; r < 4; r++) {
                size_t idx = (size_t)(row0 + r) * DD + gc;
                float v = acc[r] + bb;
                if (EPI == 1) {
                    v = fmaxf(v, 0.f) * mask_fac(mask, idx, bm);
                    ((bf16*)outp)[idx] = (bf16)v;
                } else {
                    v *= __builtin_nontemporal_load(z + idx);
                    __builtin_nontemporal_store(v, (float*)outp + idx);
                }
            }
        }
    }
}

// ---------------------------------------------------------------------------
// Pure CSR gather: out[n,:] = sum_e w[e] * t[src[e],:]   (bf16 rows, fp32 acc)
// One wave per node; 32 lanes x 16B cover one row -> 2 rows in flight/wave.
// ---------------------------------------------------------------------------
__global__ __launch_bounds__(256) void agg_k(
    const bf16* __restrict__ t, const int* __restrict__ offs,
    const int* __restrict__ cs, const float* __restrict__ cw,
    bf16* __restrict__ out) {
    int node = blockIdx.x * 4 + (threadIdx.x >> 6);
    if (node >= NN) return;
    int lane = threadIdx.x & 63;
    int half = lane >> 5;
    int lc = lane & 31;
    int beg = offs[node], end = offs[node + 1];

    float acc[8] = {};
    const unsigned short* tb = (const unsigned short*)t;
    for (int base = beg; base < end; base += 64) {
        int nume = min(64, end - base);
        int sl = 0; float wl = 0.f;
        if (lane < nume) {
            sl = __builtin_nontemporal_load(cs + base + lane);
            wl = __builtin_nontemporal_load(cw + base + lane);
        }
        int nit = (nume + 1) >> 1;
        for (int j = 0; j < nit; j++) {
            int idx = 2 * j + half;
            int s   = __shfl(sl, idx);
            float w = __shfl(wl, idx);
            u32x4 u = *(const u32x4*)(tb + (size_t)s * DD + lc * 8);
            acc[0] = fmaf(w, bflo(u.x), acc[0]);
            acc[1] = fmaf(w, bfhi(u.x), acc[1]);
            acc[2] = fmaf(w, bflo(u.y), acc[2]);
            acc[3] = fmaf(w, bfhi(u.y), acc[3]);
            acc[4] = fmaf(w, bflo(u.z), acc[4]);
            acc[5] = fmaf(w, bfhi(u.z), acc[5]);
            acc[6] = fmaf(w, bflo(u.w), acc[6]);
            acc[7] = fmaf(w, bfhi(u.w), acc[7]);
        }
    }
    #pragma unroll
    for (int i = 0; i < 8; i++) acc[i] += __shfl_xor(acc[i], 32);
    if (half == 0) {
        u16x8 o = { f2bf(acc[0]), f2bf(acc[1]), f2bf(acc[2]), f2bf(acc[3]),
                    f2bf(acc[4]), f2bf(acc[5]), f2bf(acc[6]), f2bf(acc[7]) };
        __builtin_nontemporal_store(o, (u16x8*)((unsigned short*)out + (size_t)node * DD + lc * 8));
    }
}

// ---------------------------------------------------------------------------
extern "C" void kernel_launch(void* const* d_in, const int* in_sizes, int n_in,
                              void* d_out, int out_size, void* d_ws, size_t ws_size,
                              hipStream_t stream) {
    const float* z     = (const float*)d_in[0];
    const float* omega = (const float*)d_in[1];
    const int*   eidx  = (const int*)d_in[2];
    const float* W_lin = (const float*)d_in[3];
    const float* b_lin = (const float*)d_in[4];
    const float* W_g1  = (const float*)d_in[5];
    const float* b_g1  = (const float*)d_in[6];
    const float* W_g2  = (const float*)d_in[7];
    const float* b_g2  = (const float*)d_in[8];
    const void*  mask1 = d_in[9];
    const void*  mask2 = d_in[10];

    const int* e_src = eidx;
    const int* e_dst = eidx + EE;

    char* p = (char*)d_ws;
    size_t off = 0;
    auto alloc = [&](size_t bytes) -> char* {
        char* r = p + off;
        off = (off + bytes + 255) & ~(size_t)255;
        return r;
    };
    const int NB256 = (NN + 255) / 256;          // 391
    int*   flag = (int*)  alloc(4);
    int*   cnt  = (int*)  alloc((size_t)NN * 4);
    int*   offs = (int*)  alloc(((size_t)NN + 1) * 4);
    int*   cur  = (int*)  alloc((size_t)NN * 4);
    int*   part = (int*)  alloc((size_t)NN * 4);
    int*   bsum = (int*)  alloc(512 * 4);
    int*   bpre = (int*)  alloc(512 * 4);
    float* dinv = (float*)alloc((size_t)NN * 4);
    int*   cs   = (int*)  alloc((size_t)(EE + NN) * 4);
    float* cw   = (float*)alloc((size_t)(EE + NN) * 4);
    bf16*  WtL  = (bf16*) alloc((size_t)DD * DD * 2);
    bf16*  Wt1  = (bf16*) alloc((size_t)DD * DD * 2);
    bf16*  Wt2  = (bf16*) alloc((size_t)DD * DD * 2);
    const size_t NBH = (size_t)NN * DD * 2;      // 51.2 MB bf16 slab
    bf16*  S1   = (bf16*) alloc(NBH);
    bf16*  S2   = (bf16*) alloc(NBH);

    // --- CSR build ---
    hipMemsetAsync(cnt, 0, (size_t)NN * 4, stream);
    count_deg_k<<<EE / 256, 256, 0, stream>>>(e_dst, cnt);
    scan_blk_k <<<NB256, 256, 0, stream>>>(cnt, part, bsum, dinv);
    scan_top_k <<<1, 512, 0, stream>>>(bsum, bpre, NB256);
    scan_fin_k <<<NB256, 256, 0, stream>>>(part, bpre, cnt, dinv, offs, cur, cs, cw);
    fill_csr_k <<<EE / 256, 256, 0, stream>>>(e_src, e_dst, dinv, cur, cs, cw);

    // --- weight transpose-cvt + mask probe ---
    prep_k<<<193, 256, 0, stream>>>(W_lin, W_g1, W_g2, WtL, Wt1, Wt2,
                                    (const unsigned int*)mask1, flag);

    // --- pipeline: GCNConv reordered as (A_hat . X) . W ---
    // h0 = dropout(relu(omega @ W_lin + b_lin))        (f32 A, fused cvt) -> S1
    gemm_k<1, 1><<<512, 512, 0, stream>>>(omega, WtL, b_lin, mask1, flag, nullptr, S1);
    // g1 = A_hat . h0                                   S1 -> S2
    agg_k<<<NN / 4, 256, 0, stream>>>(S1, offs, cs, cw, S2);
    // h1 = dropout(relu(g1 @ W_g1 + b_g1))              S2 -> S1
    gemm_k<1, 0><<<512, 512, 0, stream>>>(S2, Wt1, b_g1, mask2, flag, nullptr, S1);
    // g2 = A_hat . h1                                   S1 -> S2
    agg_k<<<NN / 4, 256, 0, stream>>>(S1, offs, cs, cw, S2);
    // out = z * (g2 @ W_g2 + b_g2)                      S2 -> d_out (fp32, nt)
    gemm_k<2, 0><<<512, 512, 0, stream>>>(S2, Wt2, b_g2, nullptr, flag, z, d_out);
}

// Round 6
// 1015.921 us; speedup vs baseline: 1.3143x; 1.2143x over previous
//
#include <hip/hip_runtime.h>
#include <stdint.h>

#define NN 100000
#define EE 1600000
#define DD 256
#define NSTRIP 6250          // NN / 16
#define TOTW 2048            // 256 pair-blocks * 8 waves

typedef __bf16 bf16;
typedef __attribute__((ext_vector_type(8))) __bf16 bf16x8;
typedef __attribute__((ext_vector_type(4))) float f32x4;
typedef __attribute__((ext_vector_type(4))) unsigned int u32x4;
typedef __attribute__((ext_vector_type(8))) unsigned short u16x8;

typedef __attribute__((address_space(1))) const unsigned int g_u32c;
typedef __attribute__((address_space(3))) unsigned int lds_u32;

__device__ __forceinline__ float bflo(unsigned int u) {
    union { unsigned int u; float f; } x; x.u = u << 16; return x.f;
}
__device__ __forceinline__ float bfhi(unsigned int u) {
    union { unsigned int u; float f; } x; x.u = u & 0xFFFF0000u; return x.f;
}
__device__ __forceinline__ unsigned short f2bf(float f) {
    return __builtin_bit_cast(unsigned short, (__bf16)f);
}
__device__ __forceinline__ float mask_fac(const void* mask, size_t idx, int byteMode) {
    if (byteMode) return ((const unsigned char*)mask)[idx] ? 2.0f : 0.0f;
    return ((const unsigned int*)mask)[idx] ? 2.0f : 0.0f;
}

// ---------------------------------------------------------------------------
// CSR build
// ---------------------------------------------------------------------------
__global__ void count_deg_k(const int* __restrict__ dst, int* __restrict__ cnt) {
    int e = blockIdx.x * 256 + threadIdx.x;
    if (e < EE) atomicAdd(&cnt[__builtin_nontemporal_load(dst + e)], 1);
}
__global__ __launch_bounds__(256) void scan_blk_k(const int* __restrict__ cnt,
                                                  int* __restrict__ part,
                                                  int* __restrict__ bsum,
                                                  float* __restrict__ dinv) {
    __shared__ int buf[256];
    int i = blockIdx.x * 256 + threadIdx.x;
    int v = 0;
    if (i < NN) { v = cnt[i] + 1; dinv[i] = rsqrtf((float)v); }   // +1 self-loop
    buf[threadIdx.x] = v;
    __syncthreads();
    for (int off = 1; off < 256; off <<= 1) {
        int t = (threadIdx.x >= off) ? buf[threadIdx.x - off] : 0;
        __syncthreads();
        buf[threadIdx.x] += t;
        __syncthreads();
    }
    if (i < NN) part[i] = buf[threadIdx.x];
    if (threadIdx.x == 255) bsum[blockIdx.x] = buf[255];
}
__global__ __launch_bounds__(512) void scan_top_k(const int* __restrict__ bsum,
                                                  int* __restrict__ bpre, int nb) {
    __shared__ int buf[512];
    int v = (threadIdx.x < (unsigned)nb) ? bsum[threadIdx.x] : 0;
    buf[threadIdx.x] = v;
    __syncthreads();
    for (int off = 1; off < 512; off <<= 1) {
        int t = (threadIdx.x >= off) ? buf[threadIdx.x - off] : 0;
        __syncthreads();
        buf[threadIdx.x] += t;
        __syncthreads();
    }
    if (threadIdx.x < (unsigned)nb) bpre[threadIdx.x] = buf[threadIdx.x] - v;
}
__global__ void scan_fin_k(const int* __restrict__ part, const int* __restrict__ bpre,
                           const int* __restrict__ cnt, const float* __restrict__ dinv,
                           int* __restrict__ offs, int* __restrict__ cur,
                           int* __restrict__ cs, float* __restrict__ cw) {
    int i = blockIdx.x * 256 + threadIdx.x;
    if (i >= NN) return;
    int o1 = part[i] + bpre[blockIdx.x];
    offs[i + 1] = o1;
    if (i == 0) offs[0] = 0;
    int o = o1 - (cnt[i] + 1);
    cs[o] = i;
    float di = dinv[i];
    cw[o] = di * di;
    cur[i] = o + 1;
}
__global__ void fill_csr_k(const int* __restrict__ src, const int* __restrict__ dst,
                           const float* __restrict__ dinv, int* __restrict__ cur,
                           int* __restrict__ cs, float* __restrict__ cw) {
    int e = blockIdx.x * 256 + threadIdx.x;
    if (e >= EE) return;
    int s = __builtin_nontemporal_load(src + e);
    int d = __builtin_nontemporal_load(dst + e);
    int pos = atomicAdd(&cur[d], 1);
    cs[pos] = s;
    cw[pos] = dinv[s] * dinv[d];
}

// ---------------------------------------------------------------------------
// prep: Wt[n][k] = (bf16)W[k][n] for 3 weights (blocks 0..191) + mask probe (192)
// ---------------------------------------------------------------------------
__global__ __launch_bounds__(256) void prep_k(
    const float* __restrict__ W0, const float* __restrict__ W1, const float* __restrict__ W2,
    bf16* __restrict__ T0, bf16* __restrict__ T1, bf16* __restrict__ T2,
    const unsigned int* __restrict__ m, int* __restrict__ flag) {
    int b = blockIdx.x;
    if (b == 192) {
        if (threadIdx.x < 64) {
            unsigned int v = m[threadIdx.x];
            int bad = (v > 1u && v != 0x3F800000u) ? 1 : 0;
            unsigned long long bl = __ballot(bad);
            if (threadIdx.x == 0) *flag = (bl != 0ull) ? 1 : 0;
        }
        return;
    }
    const float* W = b < 64 ? W0 : (b < 128 ? W1 : W2);
    bf16*       T  = b < 64 ? T0 : (b < 128 ? T1 : T2);
    int bb = b & 63;
    __shared__ float tile[32][33];
    int bx = bb & 7, by = bb >> 3;
    int tx = threadIdx.x & 31, ty = threadIdx.x >> 5;
    #pragma unroll
    for (int r = 0; r < 32; r += 8)
        tile[ty + r][tx] = W[(size_t)(by * 32 + ty + r) * DD + bx * 32 + tx];
    __syncthreads();
    #pragma unroll
    for (int r = 0; r < 32; r += 8)
        T[(size_t)(bx * 32 + ty + r) * DD + by * 32 + tx] = (bf16)tile[tx][ty + r];
}

// ---------------------------------------------------------------------------
// Persistent-B streaming GEMM.
// Grid: 512 blocks x 512 thr (8 waves). Block -> (pair p, n-half h); the two
// pair members share bid%8 (same XCD) so their shared A strips hit one L2.
// B panel (128 n x 256 k bf16 = 64 KB) staged once, XOR-swizzled; ZERO
// barriers after. Each wave streams 16-row A strips: 8 A-fragments loaded
// up-front (8 KB MLP), kk-outer/ni-inner MFMA (8 independent acc chains),
// epilogue after the MFMA block.
// LDS (64 KB) limits to 2 blocks/CU = 4 waves/SIMD -> 128 VGPR budget;
// __launch_bounds__(512, 2) keeps the compiler's cap above need (~100).
// EPI 1: +bias, relu, dropout(mask) -> bf16.  EPI 2: +bias, * z -> fp32.
// F32A : A is fp32 (omega), converted in-register.
// ---------------------------------------------------------------------------
template <int EPI, int F32A>
__global__ __launch_bounds__(512, 2) void gemm_k(
    const void* __restrict__ Ap, const bf16* __restrict__ Wt,
    const float* __restrict__ bias, const void* __restrict__ mask,
    const int* __restrict__ flagp, const float* __restrict__ z,
    void* __restrict__ outp) {
    __shared__ __align__(16) bf16 Bs[128 * 256];   // 64 KB

    int bid = blockIdx.x;                          // 0..511
    int p   = ((bid >> 4) << 3) | (bid & 7);       // pair 0..255
    int h   = (bid >> 3) & 1;                      // n-half
    int n0  = h * 128;
    int tid = threadIdx.x;
    int wid = tid >> 6, lane = tid & 63;
    int lr = lane & 15, lk = lane >> 4;

    // stage B: linear LDS dest + inverse-swizzled global source (rule 21)
    #pragma unroll
    for (int i = 0; i < 8; i++) {
        int c = i * 512 + tid;                     // 16B chunk 0..4095
        int n = c >> 5, pos = c & 31;
        int g = pos ^ (n & 31);
        __builtin_amdgcn_global_load_lds(
            (g_u32c*)(Wt + (size_t)(n0 + n) * DD + g * 8),
            (lds_u32*)(Bs + (size_t)c * 8), 16, 0, 0);
    }
    __syncthreads();                               // the only barrier

    float breg[8];
    #pragma unroll
    for (int ni = 0; ni < 8; ni++) breg[ni] = bias[n0 + ni * 16 + lr];
    int bm = (EPI == 1) ? *flagp : 0;

    for (int s = p * 8 + wid; s < NSTRIP; s += TOTW) {
        // ---- load all 8 A fragments (8 x 16B/lane in flight) ----
        bf16x8 afr[8];
        if (F32A) {
            const float* A = (const float*)Ap + (size_t)(s * 16 + lr) * DD + lk * 8;
            #pragma unroll
            for (int kk = 0; kk < 8; kk++) {
                float4 v0 = *(const float4*)(A + kk * 32);
                float4 v1 = *(const float4*)(A + kk * 32 + 4);
                bf16x8 f;
                f[0] = (bf16)v0.x; f[1] = (bf16)v0.y; f[2] = (bf16)v0.z; f[3] = (bf16)v0.w;
                f[4] = (bf16)v1.x; f[5] = (bf16)v1.y; f[6] = (bf16)v1.z; f[7] = (bf16)v1.w;
                afr[kk] = f;
            }
        } else {
            const bf16* A = (const bf16*)Ap + (size_t)(s * 16 + lr) * DD + lk * 8;
            #pragma unroll
            for (int kk = 0; kk < 8; kk++)
                afr[kk] = *(const bf16x8*)(A + kk * 32);
        }

        // ---- MFMA: kk outer, ni inner -> 8 independent chains ----
        f32x4 acc[8] = {};
        #pragma unroll
        for (int kk = 0; kk < 8; kk++) {
            #pragma unroll
            for (int ni = 0; ni < 8; ni++) {
                int n = ni * 16 + lr;
                int chunk = (kk * 4 + lk) ^ (n & 31);
                acc[ni] = __builtin_amdgcn_mfma_f32_16x16x32_bf16(
                    afr[kk], *(const bf16x8*)(Bs + (size_t)n * DD + chunk * 8),
                    acc[ni], 0, 0, 0);
            }
        }

        // ---- epilogue ----
        int row0 = s * 16 + lk * 4;                // C/D: row=(lane>>4)*4+reg
        #pragma unroll
        for (int ni = 0; ni < 8; ni++) {
            int gc = n0 + ni * 16 + lr;            // col = lane&15
            float bb = breg[ni];
            #pragma unroll
            for (int r = 0; r < 4; r++) {
                size_t idx = (size_t)(row0 + r) * DD + gc;
                float v = acc[ni][r] + bb;
                if (EPI == 1) {
                    v = fmaxf(v, 0.f) * mask_fac(mask, idx, bm);
                    ((bf16*)outp)[idx] = (bf16)v;
                } else {
                    v *= __builtin_nontemporal_load(z + idx);
                    __builtin_nontemporal_store(v, (float*)outp + idx);
                }
            }
        }
    }
}

// ---------------------------------------------------------------------------
// Pure CSR gather: out[n,:] = sum_e w[e] * t[src[e],:]   (bf16 rows, fp32 acc)
// One wave per node; 32 lanes x 16B cover one row -> 2 rows in flight/wave.
// ---------------------------------------------------------------------------
__global__ __launch_bounds__(256) void agg_k(
    const bf16* __restrict__ t, const int* __restrict__ offs,
    const int* __restrict__ cs, const float* __restrict__ cw,
    bf16* __restrict__ out) {
    int node = blockIdx.x * 4 + (threadIdx.x >> 6);
    if (node >= NN) return;
    int lane = threadIdx.x & 63;
    int half = lane >> 5;
    int lc = lane & 31;
    int beg = offs[node], end = offs[node + 1];

    float acc[8] = {};
    const unsigned short* tb = (const unsigned short*)t;
    for (int base = beg; base < end; base += 64) {
        int nume = min(64, end - base);
        int sl = 0; float wl = 0.f;
        if (lane < nume) {
            sl = __builtin_nontemporal_load(cs + base + lane);
            wl = __builtin_nontemporal_load(cw + base + lane);
        }
        int nit = (nume + 1) >> 1;
        for (int j = 0; j < nit; j++) {
            int idx = 2 * j + half;
            int s   = __shfl(sl, idx);
            float w = __shfl(wl, idx);
            u32x4 u = *(const u32x4*)(tb + (size_t)s * DD + lc * 8);
            acc[0] = fmaf(w, bflo(u.x), acc[0]);
            acc[1] = fmaf(w, bfhi(u.x), acc[1]);
            acc[2] = fmaf(w, bflo(u.y), acc[2]);
            acc[3] = fmaf(w, bfhi(u.y), acc[3]);
            acc[4] = fmaf(w, bflo(u.z), acc[4]);
            acc[5] = fmaf(w, bfhi(u.z), acc[5]);
            acc[6] = fmaf(w, bflo(u.w), acc[6]);
            acc[7] = fmaf(w, bfhi(u.w), acc[7]);
        }
    }
    #pragma unroll
    for (int i = 0; i < 8; i++) acc[i] += __shfl_xor(acc[i], 32);
    if (half == 0) {
        u16x8 o = { f2bf(acc[0]), f2bf(acc[1]), f2bf(acc[2]), f2bf(acc[3]),
                    f2bf(acc[4]), f2bf(acc[5]), f2bf(acc[6]), f2bf(acc[7]) };
        __builtin_nontemporal_store(o, (u16x8*)((unsigned short*)out + (size_t)node * DD + lc * 8));
    }
}

// ---------------------------------------------------------------------------
extern "C" void kernel_launch(void* const* d_in, const int* in_sizes, int n_in,
                              void* d_out, int out_size, void* d_ws, size_t ws_size,
                              hipStream_t stream) {
    const float* z     = (const float*)d_in[0];
    const float* omega = (const float*)d_in[1];
    const int*   eidx  = (const int*)d_in[2];
    const float* W_lin = (const float*)d_in[3];
    const float* b_lin = (const float*)d_in[4];
    const float* W_g1  = (const float*)d_in[5];
    const float* b_g1  = (const float*)d_in[6];
    const float* W_g2  = (const float*)d_in[7];
    const float* b_g2  = (const float*)d_in[8];
    const void*  mask1 = d_in[9];
    const void*  mask2 = d_in[10];

    const int* e_src = eidx;
    const int* e_dst = eidx + EE;

    char* p = (char*)d_ws;
    size_t off = 0;
    auto alloc = [&](size_t bytes) -> char* {
        char* r = p + off;
        off = (off + bytes + 255) & ~(size_t)255;
        return r;
    };
    const int NB256 = (NN + 255) / 256;          // 391
    int*   flag = (int*)  alloc(4);
    int*   cnt  = (int*)  alloc((size_t)NN * 4);
    int*   offs = (int*)  alloc(((size_t)NN + 1) * 4);
    int*   cur  = (int*)  alloc((size_t)NN * 4);
    int*   part = (int*)  alloc((size_t)NN * 4);
    int*   bsum = (int*)  alloc(512 * 4);
    int*   bpre = (int*)  alloc(512 * 4);
    float* dinv = (float*)alloc((size_t)NN * 4);
    int*   cs   = (int*)  alloc((size_t)(EE + NN) * 4);
    float* cw   = (float*)alloc((size_t)(EE + NN) * 4);
    bf16*  WtL  = (bf16*) alloc((size_t)DD * DD * 2);
    bf16*  Wt1  = (bf16*) alloc((size_t)DD * DD * 2);
    bf16*  Wt2  = (bf16*) alloc((size_t)DD * DD * 2);
    const size_t NBH = (size_t)NN * DD * 2;      // 51.2 MB bf16 slab
    bf16*  S1   = (bf16*) alloc(NBH);
    bf16*  S2   = (bf16*) alloc(NBH);

    // --- CSR build ---
    hipMemsetAsync(cnt, 0, (size_t)NN * 4, stream);
    count_deg_k<<<EE / 256, 256, 0, stream>>>(e_dst, cnt);
    scan_blk_k <<<NB256, 256, 0, stream>>>(cnt, part, bsum, dinv);
    scan_top_k <<<1, 512, 0, stream>>>(bsum, bpre, NB256);
    scan_fin_k <<<NB256, 256, 0, stream>>>(part, bpre, cnt, dinv, offs, cur, cs, cw);
    fill_csr_k <<<EE / 256, 256, 0, stream>>>(e_src, e_dst, dinv, cur, cs, cw);

    // --- weight transpose-cvt + mask probe ---
    prep_k<<<193, 256, 0, stream>>>(W_lin, W_g1, W_g2, WtL, Wt1, Wt2,
                                    (const unsigned int*)mask1, flag);

    // --- pipeline: GCNConv reordered as (A_hat . X) . W ---
    // h0 = dropout(relu(omega @ W_lin + b_lin))        (f32 A, fused cvt) -> S1
    gemm_k<1, 1><<<512, 512, 0, stream>>>(omega, WtL, b_lin, mask1, flag, nullptr, S1);
    // g1 = A_hat . h0                                   S1 -> S2
    agg_k<<<NN / 4, 256, 0, stream>>>(S1, offs, cs, cw, S2);
    // h1 = dropout(relu(g1 @ W_g1 + b_g1))              S2 -> S1
    gemm_k<1, 0><<<512, 512, 0, stream>>>(S2, Wt1, b_g1, mask2, flag, nullptr, S1);
    // g2 = A_hat . h1                                   S1 -> S2
    agg_k<<<NN / 4, 256, 0, stream>>>(S1, offs, cs, cw, S2);
    // out = z * (g2 @ W_g2 + b_g2)                      S2 -> d_out (fp32, nt)
    gemm_k<2, 0><<<512, 512, 0, stream>>>(S2, Wt2, b_g2, nullptr, flag, z, d_out);
}

// Round 8
// 655.790 us; speedup vs baseline: 2.0361x; 1.5492x over previous
//
#include <hip/hip_runtime.h>
#include <stdint.h>

#define NN 100000
#define EE 1600000
#define DD 256

typedef __bf16 bf16;
typedef __attribute__((ext_vector_type(8))) __bf16 bf16x8;
typedef __attribute__((ext_vector_type(4))) float f32x4;
typedef __attribute__((ext_vector_type(4))) unsigned int u32x4;
typedef __attribute__((ext_vector_type(8))) unsigned short u16x8;

typedef __attribute__((address_space(1))) const unsigned int g_u32c;
typedef __attribute__((address_space(3))) unsigned int lds_u32;

__device__ __forceinline__ float bflo(unsigned int u) {
    union { unsigned int u; float f; } x; x.u = u << 16; return x.f;
}
__device__ __forceinline__ float bfhi(unsigned int u) {
    union { unsigned int u; float f; } x; x.u = u & 0xFFFF0000u; return x.f;
}
__device__ __forceinline__ unsigned short f2bf(float f) {
    return __builtin_bit_cast(unsigned short, (__bf16)f);
}

// ---------------------------------------------------------------------------
// CSR build
// ---------------------------------------------------------------------------
__global__ void count_deg_k(const int* __restrict__ dst, int* __restrict__ cnt) {
    int e = blockIdx.x * 256 + threadIdx.x;
    if (e < EE) atomicAdd(&cnt[__builtin_nontemporal_load(dst + e)], 1);
}
__global__ __launch_bounds__(256) void scan_blk_k(const int* __restrict__ cnt,
                                                  int* __restrict__ part,
                                                  int* __restrict__ bsum,
                                                  float* __restrict__ dinv) {
    __shared__ int buf[256];
    int i = blockIdx.x * 256 + threadIdx.x;
    int v = 0;
    if (i < NN) { v = cnt[i] + 1; dinv[i] = rsqrtf((float)v); }   // +1 self-loop
    buf[threadIdx.x] = v;
    __syncthreads();
    for (int off = 1; off < 256; off <<= 1) {
        int t = (threadIdx.x >= off) ? buf[threadIdx.x - off] : 0;
        __syncthreads();
        buf[threadIdx.x] += t;
        __syncthreads();
    }
    if (i < NN) part[i] = buf[threadIdx.x];
    if (threadIdx.x == 255) bsum[blockIdx.x] = buf[255];
}
__global__ __launch_bounds__(512) void scan_top_k(const int* __restrict__ bsum,
                                                  int* __restrict__ bpre, int nb) {
    __shared__ int buf[512];
    int v = (threadIdx.x < (unsigned)nb) ? bsum[threadIdx.x] : 0;
    buf[threadIdx.x] = v;
    __syncthreads();
    for (int off = 1; off < 512; off <<= 1) {
        int t = (threadIdx.x >= off) ? buf[threadIdx.x - off] : 0;
        __syncthreads();
        buf[threadIdx.x] += t;
        __syncthreads();
    }
    if (threadIdx.x < (unsigned)nb) bpre[threadIdx.x] = buf[threadIdx.x] - v;
}
__global__ void scan_fin_k(const int* __restrict__ part, const int* __restrict__ bpre,
                           const int* __restrict__ cnt, const float* __restrict__ dinv,
                           int* __restrict__ offs, int* __restrict__ cur,
                           int* __restrict__ cs, float* __restrict__ cw) {
    int i = blockIdx.x * 256 + threadIdx.x;
    if (i >= NN) return;
    int o1 = part[i] + bpre[blockIdx.x];
    offs[i + 1] = o1;
    if (i == 0) offs[0] = 0;
    int o = o1 - (cnt[i] + 1);
    cs[o] = i;
    float di = dinv[i];
    cw[o] = di * di;
    cur[i] = o + 1;
}
__global__ void fill_csr_k(const int* __restrict__ src, const int* __restrict__ dst,
                           const float* __restrict__ dinv, int* __restrict__ cur,
                           int* __restrict__ cs, float* __restrict__ cw) {
    int e = blockIdx.x * 256 + threadIdx.x;
    if (e >= EE) return;
    int s = __builtin_nontemporal_load(src + e);
    int d = __builtin_nontemporal_load(dst + e);
    int pos = atomicAdd(&cur[d], 1);
    cs[pos] = s;
    cw[pos] = dinv[s] * dinv[d];
}

// ---------------------------------------------------------------------------
// prep: Wt[n][k] = (bf16)W[k][n] for 3 weights (blocks 0..191) + mask probe (192)
// ---------------------------------------------------------------------------
__global__ __launch_bounds__(256) void prep_k(
    const float* __restrict__ W0, const float* __restrict__ W1, const float* __restrict__ W2,
    bf16* __restrict__ T0, bf16* __restrict__ T1, bf16* __restrict__ T2,
    const unsigned int* __restrict__ m, int* __restrict__ flag) {
    int b = blockIdx.x;
    if (b == 192) {
        if (threadIdx.x < 64) {
            unsigned int v = m[threadIdx.x];
            int bad = (v > 1u && v != 0x3F800000u) ? 1 : 0;
            unsigned long long bl = __ballot(bad);
            if (threadIdx.x == 0) *flag = (bl != 0ull) ? 1 : 0;
        }
        return;
    }
    const float* W = b < 64 ? W0 : (b < 128 ? W1 : W2);
    bf16*       T  = b < 64 ? T0 : (b < 128 ? T1 : T2);
    int bb = b & 63;
    __shared__ float tile[32][33];
    int bx = bb & 7, by = bb >> 3;
    int tx = threadIdx.x & 31, ty = threadIdx.x >> 5;
    #pragma unroll
    for (int r = 0; r < 32; r += 8)
        tile[ty + r][tx] = W[(size_t)(by * 32 + ty + r) * DD + bx * 32 + tx];
    __syncthreads();
    #pragma unroll
    for (int r = 0; r < 32; r += 8)
        T[(size_t)(bx * 32 + ty + r) * DD + by * 32 + tx] = (bf16)tile[tx][ty + r];
}

// ---------------------------------------------------------------------------
// omega fp32 -> bf16
// ---------------------------------------------------------------------------
__global__ void cvt_rows_k(const float* __restrict__ in, unsigned short* __restrict__ out) {
    int i = blockIdx.x * 256 + threadIdx.x;
    float4 v = ((const float4*)in)[i];
    ushort4 o = { f2bf(v.x), f2bf(v.y), f2bf(v.z), f2bf(v.w) };
    ((ushort4*)out)[i] = o;
}

// ---------------------------------------------------------------------------
// bf16 MFMA GEMM (R2-proven skeleton): out[M,256] = A[M,256] @ W, W as Wt[n][k].
// 128x128 tile, BK=64, 256 thr = 4 waves (2x2), 4x4 16x16x32 frags/wave.
// Linear LDS, global_load_lds staging, 2 barriers per K-step.
// OPERAND-SWAPPED MFMA: mfma(bfr, af) -> frag holds rows m=mi*16+(lane&15),
// cols n=ni*16+(lane>>4)*4+reg -> 4 consecutive cols/lane -> vector epilogue.
// Grid: 1D 1568; bid -> m=((bid>>4)<<3)|(bid&7), h=(bid>>3)&1 so the two
// n-halves of the same A-rows share bid%8 (same XCD L2).
// EPI 1: +bias, relu, dropout(mask) -> bf16.  EPI 2: +bias, * z -> fp32 nt.
// ---------------------------------------------------------------------------
template <int ID, int EPI>
__global__ __launch_bounds__(256) void gemm_k(
    const bf16* __restrict__ A, const bf16* __restrict__ Wt,
    const float* __restrict__ bias, const void* __restrict__ mask,
    const int* __restrict__ flagp, const float* __restrict__ z,
    void* __restrict__ outp) {
    __shared__ __align__(16) bf16 As[128 * 64];
    __shared__ __align__(16) bf16 Bs[128 * 64];

    int bid = blockIdx.x;
    int m   = ((bid >> 4) << 3) | (bid & 7);
    int h   = (bid >> 3) & 1;
    int m0  = m * 128, n0 = h * 128;
    if (m0 >= NN) return;
    int tid = threadIdx.x;
    int wid = tid >> 6, lane = tid & 63;
    int wm = wid >> 1, wn = wid & 1;
    int lr = lane & 15, lk = lane >> 4;

    f32x4 acc[4][4] = {};

    for (int k0 = 0; k0 < DD; k0 += 64) {
        #pragma unroll
        for (int i = 0; i < 4; i++) {
            int f = i * 256 + tid;            // 16B chunk id, 1024 per tile
            int row = f >> 3;
            int c   = (f & 7) * 8;
            int gr = m0 + row; if (gr > NN - 1) gr = NN - 1;
            __builtin_amdgcn_global_load_lds(
                (g_u32c*)(A + (size_t)gr * DD + k0 + c),
                (lds_u32*)(As + (size_t)f * 8), 16, 0, 0);
            __builtin_amdgcn_global_load_lds(
                (g_u32c*)(Wt + (size_t)(n0 + row) * DD + k0 + c),
                (lds_u32*)(Bs + (size_t)f * 8), 16, 0, 0);
        }
        __syncthreads();
        #pragma unroll
        for (int kk = 0; kk < 2; kk++) {
            bf16x8 af[4], bfr[4];
            #pragma unroll
            for (int mi = 0; mi < 4; mi++)
                af[mi] = *(const bf16x8*)(As + (wm * 64 + mi * 16 + lr) * 64 + kk * 32 + lk * 8);
            #pragma unroll
            for (int ni = 0; ni < 4; ni++)
                bfr[ni] = *(const bf16x8*)(Bs + (wn * 64 + ni * 16 + lr) * 64 + kk * 32 + lk * 8);
            #pragma unroll
            for (int mi = 0; mi < 4; mi++)
                #pragma unroll
                for (int ni = 0; ni < 4; ni++)
                    acc[mi][ni] = __builtin_amdgcn_mfma_f32_16x16x32_bf16(
                        bfr[ni], af[mi], acc[mi][ni], 0, 0, 0);   // swapped
        }
        __syncthreads();
    }

    int bm = (EPI == 1) ? *flagp : 0;
    #pragma unroll
    for (int mi = 0; mi < 4; mi++) {
        int gr = m0 + wm * 64 + mi * 16 + lr;          // row = lane&15
        if (gr >= NN) continue;
        #pragma unroll
        for (int ni = 0; ni < 4; ni++) {
            int gc = n0 + wn * 64 + ni * 16 + lk * 4;  // 4 consecutive cols
            size_t idx = (size_t)gr * DD + gc;
            float4 b4 = *(const float4*)(bias + gc);
            float v0 = acc[mi][ni][0] + b4.x;
            float v1 = acc[mi][ni][1] + b4.y;
            float v2 = acc[mi][ni][2] + b4.z;
            float v3 = acc[mi][ni][3] + b4.w;
            if (EPI == 1) {
                v0 = fmaxf(v0, 0.f); v1 = fmaxf(v1, 0.f);
                v2 = fmaxf(v2, 0.f); v3 = fmaxf(v3, 0.f);
                if (bm) {
                    uchar4 u = *(const uchar4*)((const unsigned char*)mask + idx);
                    v0 *= u.x ? 2.f : 0.f; v1 *= u.y ? 2.f : 0.f;
                    v2 *= u.z ? 2.f : 0.f; v3 *= u.w ? 2.f : 0.f;
                } else {
                    uint4 u = *(const uint4*)((const unsigned int*)mask + idx);
                    v0 *= u.x ? 2.f : 0.f; v1 *= u.y ? 2.f : 0.f;
                    v2 *= u.z ? 2.f : 0.f; v3 *= u.w ? 2.f : 0.f;
                }
                ushort4 o = { f2bf(v0), f2bf(v1), f2bf(v2), f2bf(v3) };
                *(ushort4*)((unsigned short*)outp + idx) = o;
            } else {
                f32x4 zz = __builtin_nontemporal_load((const f32x4*)(z + idx));
                f32x4 o = { v0 * zz.x, v1 * zz.y, v2 * zz.z, v3 * zz.w };
                __builtin_nontemporal_store(o, (f32x4*)((float*)outp + idx));
            }
        }
    }
}

// ---------------------------------------------------------------------------
// Pure CSR gather: out[n,:] = sum_e w[e] * t[src[e],:]   (bf16 rows, fp32 acc)
// ---------------------------------------------------------------------------
__global__ __launch_bounds__(256) void agg_k(
    const bf16* __restrict__ t, const int* __restrict__ offs,
    const int* __restrict__ cs, const float* __restrict__ cw,
    bf16* __restrict__ out) {
    int node = blockIdx.x * 4 + (threadIdx.x >> 6);
    if (node >= NN) return;
    int lane = threadIdx.x & 63;
    int half = lane >> 5;
    int lc = lane & 31;
    int beg = offs[node], end = offs[node + 1];

    float acc[8] = {};
    const unsigned short* tb = (const unsigned short*)t;
    for (int base = beg; base < end; base += 64) {
        int nume = min(64, end - base);
        int sl = 0; float wl = 0.f;
        if (lane < nume) {
            sl = __builtin_nontemporal_load(cs + base + lane);
            wl = __builtin_nontemporal_load(cw + base + lane);
        }
        int nit = (nume + 1) >> 1;
        for (int j = 0; j < nit; j++) {
            int idx = 2 * j + half;
            int s   = __shfl(sl, idx);
            float w = __shfl(wl, idx);
            u32x4 u = *(const u32x4*)(tb + (size_t)s * DD + lc * 8);
            acc[0] = fmaf(w, bflo(u.x), acc[0]);
            acc[1] = fmaf(w, bfhi(u.x), acc[1]);
            acc[2] = fmaf(w, bflo(u.y), acc[2]);
            acc[3] = fmaf(w, bfhi(u.y), acc[3]);
            acc[4] = fmaf(w, bflo(u.z), acc[4]);
            acc[5] = fmaf(w, bfhi(u.z), acc[5]);
            acc[6] = fmaf(w, bflo(u.w), acc[6]);
            acc[7] = fmaf(w, bfhi(u.w), acc[7]);
        }
    }
    #pragma unroll
    for (int i = 0; i < 8; i++) acc[i] += __shfl_xor(acc[i], 32);
    if (half == 0) {
        u16x8 o = { f2bf(acc[0]), f2bf(acc[1]), f2bf(acc[2]), f2bf(acc[3]),
                    f2bf(acc[4]), f2bf(acc[5]), f2bf(acc[6]), f2bf(acc[7]) };
        __builtin_nontemporal_store(o, (u16x8*)((unsigned short*)out + (size_t)node * DD + lc * 8));
    }
}

// ---------------------------------------------------------------------------
extern "C" void kernel_launch(void* const* d_in, const int* in_sizes, int n_in,
                              void* d_out, int out_size, void* d_ws, size_t ws_size,
                              hipStream_t stream) {
    const float* z     = (const float*)d_in[0];
    const float* omega = (const float*)d_in[1];
    const int*   eidx  = (const int*)d_in[2];
    const float* W_lin = (const float*)d_in[3];
    const float* b_lin = (const float*)d_in[4];
    const float* W_g1  = (const float*)d_in[5];
    const float* b_g1  = (const float*)d_in[6];
    const float* W_g2  = (const float*)d_in[7];
    const float* b_g2  = (const float*)d_in[8];
    const void*  mask1 = d_in[9];
    const void*  mask2 = d_in[10];

    const int* e_src = eidx;
    const int* e_dst = eidx + EE;

    char* p = (char*)d_ws;
    size_t off = 0;
    auto alloc = [&](size_t bytes) -> char* {
        char* r = p + off;
        off = (off + bytes + 255) & ~(size_t)255;
        return r;
    };
    const int NB256 = (NN + 255) / 256;          // 391
    int*   flag = (int*)  alloc(4);
    int*   cnt  = (int*)  alloc((size_t)NN * 4);
    int*   offs = (int*)  alloc(((size_t)NN + 1) * 4);
    int*   cur  = (int*)  alloc((size_t)NN * 4);
    int*   part = (int*)  alloc((size_t)NN * 4);
    int*   bsum = (int*)  alloc(512 * 4);
    int*   bpre = (int*)  alloc(512 * 4);
    float* dinv = (float*)alloc((size_t)NN * 4);
    int*   cs   = (int*)  alloc((size_t)(EE + NN) * 4);
    float* cw   = (float*)alloc((size_t)(EE + NN) * 4);
    bf16*  WtL  = (bf16*) alloc((size_t)DD * DD * 2);
    bf16*  Wt1  = (bf16*) alloc((size_t)DD * DD * 2);
    bf16*  Wt2  = (bf16*) alloc((size_t)DD * DD * 2);
    const size_t NBH = (size_t)NN * DD * 2;      // 51.2 MB bf16 slab
    bf16*  S1   = (bf16*) alloc(NBH);
    bf16*  S2   = (bf16*) alloc(NBH);
    bf16*  S0   = (bf16*)d_out;   // omega-bf16 scratch in d_out (overwritten by G2 at the end)

    // --- CSR build ---
    (void)hipMemsetAsync(cnt, 0, (size_t)NN * 4, stream);
    count_deg_k<<<EE / 256, 256, 0, stream>>>(e_dst, cnt);
    scan_blk_k <<<NB256, 256, 0, stream>>>(cnt, part, bsum, dinv);
    scan_top_k <<<1, 512, 0, stream>>>(bsum, bpre, NB256);
    scan_fin_k <<<NB256, 256, 0, stream>>>(part, bpre, cnt, dinv, offs, cur, cs, cw);
    fill_csr_k <<<EE / 256, 256, 0, stream>>>(e_src, e_dst, dinv, cur, cs, cw);

    // --- weight transpose-cvt + mask probe; omega -> bf16 ---
    prep_k<<<193, 256, 0, stream>>>(W_lin, W_g1, W_g2, WtL, Wt1, Wt2,
                                    (const unsigned int*)mask1, flag);
    cvt_rows_k<<<NN * DD / 4 / 256, 256, 0, stream>>>(omega, (unsigned short*)S0);

    // --- pipeline: GCNConv reordered as (A_hat . X) . W ---
    const int GG = 1568;   // 784 m-blocks x 2 n-halves, XCD-paired
    // h0 = dropout(relu(omega @ W_lin + b_lin))         S0 -> S1
    gemm_k<0, 1><<<GG, 256, 0, stream>>>(S0, WtL, b_lin, mask1, flag, nullptr, S1);
    // g1 = A_hat . h0                                   S1 -> S2
    agg_k<<<NN / 4, 256, 0, stream>>>(S1, offs, cs, cw, S2);
    // h1 = dropout(relu(g1 @ W_g1 + b_g1))              S2 -> S1
    gemm_k<1, 1><<<GG, 256, 0, stream>>>(S2, Wt1, b_g1, mask2, flag, nullptr, S1);
    // g2 = A_hat . h1                                   S1 -> S2
    agg_k<<<NN / 4, 256, 0, stream>>>(S1, offs, cs, cw, S2);
    // out = z * (g2 @ W_g2 + b_g2)                      S2 -> d_out (fp32, nt)
    gemm_k<2, 2><<<GG, 256, 0, stream>>>(S2, Wt2, b_g2, nullptr, flag, z, d_out);
}